// Round 2
// 1625.417 us; speedup vs baseline: 1.0037x; 1.0037x over previous
//
#include <hip/hip_runtime.h>
#include <hip/hip_bf16.h>

// NMT forward, MI355X. f32 I/O (per reference dtypes), bf16 MFMA internally.
// Simplifications: softmax shift-invariance => attention weights / ctx are
// time-invariant; teacher forcing => all input-side gate pre-activations are
// one GEMM (A = [dec_emb[tok] | ctx] concat, K=1024). Only h@W_hh.T is
// sequential. Projection deferred to one big GEMM over all 49 h_t.
//
// R1: gemm_bt upgraded to the m97 structure: global_load_lds (16B) staging
//     (A+B in MODE 2, B-only in MODES 0/1), bijective XCD swizzle with
//     column-major tile order (B-tile L2 reuse across the 25 M-sweeps).
// R2: identical resubmit — R1 bench was an infra failure (container), no
//     kernel signal. Static re-audit found no hang/crash vector.

typedef __attribute__((ext_vector_type(8))) short bf16x8;
typedef __attribute__((ext_vector_type(4))) short short4v;
typedef __attribute__((ext_vector_type(4))) float f32x4;

__device__ __forceinline__ short f2b(float f) {
    union { float f; unsigned u; } x;
    x.f = f;
    unsigned r = (x.u + 0x7FFFu + ((x.u >> 16) & 1u)) >> 16;
    return (short)r;
}

// async global->LDS DMA, 16B per lane. LDS dest must be wave-uniform base +
// lane*16 (our chunk layout is exactly lane-linear). vmcnt-tracked; the
// __syncthreads() after issue drains vmcnt(0) so the tile is visible.
__device__ __forceinline__ void gload16(const short* g, short* l) {
    __builtin_amdgcn_global_load_lds(
        (const __attribute__((address_space(1))) unsigned int*)g,
        (__attribute__((address_space(3))) unsigned int*)l,
        16, 0, 0);
}

// f32 -> bf16 bulk convert (weights), one float4 per thread
__global__ __launch_bounds__(256)
void cvt_kernel(const float* __restrict__ in, short* __restrict__ out, int n4) {
    int i = blockIdx.x * 256 + threadIdx.x;
    if (i < n4) {
        float4 x = ((const float4*)in)[i];
        short4v v;
        v[0] = f2b(x.x); v[1] = f2b(x.y); v[2] = f2b(x.z); v[3] = f2b(x.w);
        ((short4v*)out)[i] = v;
    }
}

// ---------------------------------------------------------------------------
// Tiled MFMA GEMM: out[m][n] = sum_k A[m][k]*Bt[n][k] + bias. 128x128 tile,
// BK=32, 256 thr (4 waves 2x2). B is pre-converted bf16 (row-major, K=1024
// contiguous), staged via global_load_lds. A staged with inline f32->bf16 cvt
// (modes 0/1) or global_load_lds direct (mode 2).
// MODE 0: A = [enc_emb[src] | pos_emb[pos]], N=512,  out = ENCO (f32), +cat_b
// MODE 1: A = [dec_emb[tok] | ctx[b]],      N=4096, out = PRE (f32), +b_ih+b_hh
// MODE 2: A = h_all (bf16),                 N=32000, out = logits (f32), +proj_b
// ---------------------------------------------------------------------------
template <int MODE>
__global__ __launch_bounds__(256, 2)
void gemm_bt(const float* __restrict__ Af, const float* __restrict__ Af2,
             const short* __restrict__ Ab,
             const int* __restrict__ idx1, const int* __restrict__ idx2,
             const short* __restrict__ Bt,
             const float* __restrict__ bias1, const float* __restrict__ bias2,
             float* __restrict__ Out) {
    constexpr int OUTS = (MODE == 0) ? 512 : ((MODE == 1) ? 4096 : 32000);

    __shared__ short As[128 * 32];
    __shared__ short Bs[128 * 32];

    const int tid = threadIdx.x;
    const int lane = tid & 63;
    const int wave = tid >> 6;
    const int wm = wave >> 1, wn = wave & 1;
    const int quad = lane >> 4;
    const int l15 = lane & 15;

    // block -> tile mapping. MODES 1/2: bijective XCD swizzle (8 chunks of
    // consecutive flat ids per XCD) + column-major (M fastest) order so each
    // 256KB B-tile stays L2-resident for its 25 M-tile uses.
    int mt, nt;
    if constexpr (MODE == 0) {
        mt = blockIdx.y; nt = blockIdx.x;
    } else if constexpr (MODE == 1) {
        const int f = blockIdx.y * 32 + blockIdx.x;   // 800 blocks, 800%8==0
        const int g = (f & 7) * 100 + (f >> 3);
        mt = g % 25; nt = g / 25;                      // nt in [0,32)
    } else {
        const int f = blockIdx.y * 250 + blockIdx.x;   // 6250 blocks, 6250%8==2
        const int xcd = f & 7, rk = f >> 3;            // m204 bijective variant
        const int g = (xcd < 2) ? xcd * 782 + rk : 1564 + (xcd - 2) * 781 + rk;
        mt = g % 25; nt = g / 25;                      // nt in [0,250)
    }
    const int tm = mt * 128;
    const int tn = nt * 128;

    f32x4 acc[4][4];
    const f32x4 vzero = {0.f, 0.f, 0.f, 0.f};
#pragma unroll
    for (int mi = 0; mi < 4; mi++)
#pragma unroll
        for (int ni = 0; ni < 4; ni++) acc[mi][ni] = vzero;

    // staging: 512 chunks of 8 elems (16B bf16); chunk c -> row c>>2, koff (c&3)*8
    // LDS byte offset of chunk c is c*16: lane-linear per wave (DMA-compatible).
    const int c0 = tid, c1 = tid + 256;
    const int r0 = c0 >> 2, r1 = c1 >> 2;
    const int o0 = (c0 & 3) * 8, o1 = (c1 & 3) * 8;

    const float *a0_lo = nullptr, *a0_hi = nullptr, *a1_lo = nullptr, *a1_hi = nullptr;
    const short *ab0 = nullptr, *ab1 = nullptr;
    if constexpr (MODE == 0) {
        const int g0 = tm + r0, g1 = tm + r1;            // < 3200 exact
        a0_lo = Af + idx1[g0] * 512;                     // enc_emb[src]
        a0_hi = Af2 + idx2[g0] * 512 - 512;              // pos_emb[pos]
        a1_lo = Af + idx1[g1] * 512;
        a1_hi = Af2 + idx2[g1] * 512 - 512;
    } else if constexpr (MODE == 1) {
        int g0 = tm + r0; if (g0 > 3135) g0 = 3135;      // clamp pad rows
        int g1 = tm + r1; if (g1 > 3135) g1 = 3135;
        // row m = t*64 + b ; token = tgt[b*50 + t]
        a0_lo = Af + idx1[(g0 & 63) * 50 + (g0 >> 6)] * 512;
        a0_hi = Af2 + (g0 & 63) * 512 - 512;             // ctx[b]
        a1_lo = Af + idx1[(g1 & 63) * 50 + (g1 >> 6)] * 512;
        a1_hi = Af2 + (g1 & 63) * 512 - 512;
    } else {
        ab0 = Ab + (tm + r0) * 1024;                     // rows < 3200, in-bounds
        ab1 = Ab + (tm + r1) * 1024;
    }
    const short* pb0 = Bt + (tn + r0) * 1024;
    const short* pb1 = Bt + (tn + r1) * 1024;

    for (int k0 = 0; k0 < 1024; k0 += 32) {
        const int ka0 = k0 + o0, ka1 = k0 + o1;
        bf16x8 va0, va1;
        if constexpr (MODE != 2) {
            // A gather + inline f32->bf16 (issued before the barrier so the
            // global loads overlap the previous iteration's MFMA phase)
            const float* p0 = (ka0 < 512) ? (a0_lo + ka0) : (a0_hi + ka0);
            const float* p1 = (ka1 < 512) ? (a1_lo + ka1) : (a1_hi + ka1);
            float4 x0 = *(const float4*)p0, y0 = *(const float4*)(p0 + 4);
            float4 x1 = *(const float4*)p1, y1 = *(const float4*)(p1 + 4);
            va0[0] = f2b(x0.x); va0[1] = f2b(x0.y); va0[2] = f2b(x0.z); va0[3] = f2b(x0.w);
            va0[4] = f2b(y0.x); va0[5] = f2b(y0.y); va0[6] = f2b(y0.z); va0[7] = f2b(y0.w);
            va1[0] = f2b(x1.x); va1[1] = f2b(x1.y); va1[2] = f2b(x1.z); va1[3] = f2b(x1.w);
            va1[4] = f2b(y1.x); va1[5] = f2b(y1.y); va1[6] = f2b(y1.z); va1[7] = f2b(y1.w);
        }

        __syncthreads();  // previous iter's fragment reads complete
        gload16(pb0 + ka0, &Bs[r0 * 32 + o0]);
        gload16(pb1 + ka1, &Bs[r1 * 32 + o1]);
        if constexpr (MODE == 2) {
            gload16(ab0 + ka0, &As[r0 * 32 + o0]);
            gload16(ab1 + ka1, &As[r1 * 32 + o1]);
        } else {
            *(bf16x8*)&As[r0 * 32 + o0] = va0;
            *(bf16x8*)&As[r1 * 32 + o1] = va1;
        }
        __syncthreads();  // drains vmcnt(0)+lgkmcnt(0): tiles visible

        bf16x8 af[4], bfr[4];
#pragma unroll
        for (int mi = 0; mi < 4; mi++)
            af[mi] = *(const bf16x8*)&As[(wm * 64 + mi * 16 + l15) * 32 + quad * 8];
#pragma unroll
        for (int ni = 0; ni < 4; ni++)
            bfr[ni] = *(const bf16x8*)&Bs[(wn * 64 + ni * 16 + l15) * 32 + quad * 8];
#pragma unroll
        for (int mi = 0; mi < 4; mi++)
#pragma unroll
            for (int ni = 0; ni < 4; ni++)
                acc[mi][ni] = __builtin_amdgcn_mfma_f32_16x16x32_bf16(
                    af[mi], bfr[ni], acc[mi][ni], 0, 0, 0);
    }

    // epilogue: D row = quad*4 + r (M), col = l15 (N)   [m89-verified layout]
    const int gm_base = tm + wm * 64;
    const int gn_base = tn + wn * 64;
#pragma unroll
    for (int mi = 0; mi < 4; mi++) {
#pragma unroll
        for (int ni = 0; ni < 4; ni++) {
            const int gn = gn_base + ni * 16 + l15;
            float bias = bias1[gn];
            if constexpr (MODE == 1) bias += bias2[gn];
#pragma unroll
            for (int r = 0; r < 4; r++) {
                const int gm = gm_base + mi * 16 + quad * 4 + r;
                float v = acc[mi][ni][r] + bias;
                if constexpr (MODE == 0) {
                    Out[gm * OUTS + gn] = v;
                } else {
                    if (gm < 3136) Out[gm * OUTS + gn] = v;
                }
            }
        }
    }
}

// ---------------------------------------------------------------------------
// h0 = relu(mean_s(enc_out) @ scale_W.T + scale_b); h bf16, c f32. block=batch.
// ---------------------------------------------------------------------------
__global__ __launch_bounds__(256)
void h0_kernel(const float* __restrict__ enc, const float* __restrict__ sW,
               const float* __restrict__ sb, short* __restrict__ h0out,
               float* __restrict__ cst) {
    __shared__ float avg[512];
    const int b = blockIdx.x;
    const int tid = threadIdx.x;
    for (int e = tid; e < 512; e += 256) {
        float s = 0.f;
        for (int ss = 0; ss < 50; ss++) s += enc[(b * 50 + ss) * 512 + e];
        avg[e] = s * (1.0f / 50.0f);
    }
    __syncthreads();
    for (int r = tid; r < 1024; r += 256) {
        float s = sb[r];
        const float4* wr = (const float4*)(sW + r * 512);
        const float4* av = (const float4*)avg;
#pragma unroll 4
        for (int e = 0; e < 128; e++) {
            float4 w = wr[e], a = av[e];
            s += w.x * a.x + w.y * a.y + w.z * a.z + w.w * a.w;
        }
        s = fmaxf(s, 0.f);
        h0out[b * 1024 + r] = f2b(s);
        cst[b * 1024 + r] = s;  // c0 = h0
    }
}

// ---------------------------------------------------------------------------
// time-invariant attention: aw = renorm(mask(softmax(enc_out . wE)));
// ctx = sum_s aw * enc_out.  (h-term + attn_b drop out of shifted softmax)
// ---------------------------------------------------------------------------
__global__ __launch_bounds__(256)
void attn_kernel(const float* __restrict__ enc, const float* __restrict__ attn_W,
                 const int* __restrict__ src, float* __restrict__ ctx) {
    __shared__ float wE[512];
    __shared__ float part[64][4];
    __shared__ float aws[64];
    const int b = blockIdx.x;
    const int tid = threadIdx.x;
    for (int e = tid; e < 512; e += 256) wE[e] = attn_W[e];
    __syncthreads();
    const int ss = tid >> 2, q = tid & 3;
    float p = 0.f;
    if (ss < 50) {
        const float* row = enc + (b * 50 + ss) * 512;
        for (int e = q * 128; e < q * 128 + 128; e++) p += row[e] * wE[e];
    }
    part[ss][q] = p;
    __syncthreads();
    if (tid < 64) aws[tid] = part[tid][0] + part[tid][1] + part[tid][2] + part[tid][3];
    __syncthreads();
    if (tid == 0) {
        float mx = -1e30f;
        for (int s = 0; s < 50; s++) mx = fmaxf(mx, aws[s]);
        float sum = 0.f;
        for (int s = 0; s < 50; s++) {
            float v = (src[b * 50 + s] == 0) ? 0.f : expf(aws[s] - mx);
            aws[s] = v;
            sum += v;
        }
        float inv = 1.f / sum;
        for (int s = 0; s < 50; s++) aws[s] *= inv;
    }
    __syncthreads();
    for (int e = tid; e < 512; e += 256) {
        float s = 0.f;
        for (int ss2 = 0; ss2 < 50; ss2++) s += aws[ss2] * enc[(b * 50 + ss2) * 512 + e];
        ctx[b * 512 + e] = s;
    }
}

// ---------------------------------------------------------------------------
// one LSTM step: gates = pre_t + h_prev @ W_hh.T; cell update. 256 blocks,
// block owns j in [j0,j0+4): A = 16 W_hh rows {(m>>2)*1024 + j0 + (m&3)},
// wave w's B = h rows w*16..w*16+15. c f32 in scratch.
// ---------------------------------------------------------------------------
__global__ __launch_bounds__(256)
void lstm_step(const short* __restrict__ hprev, short* __restrict__ hnext,
               const float* __restrict__ pre_t, const short* __restrict__ whh,
               float* __restrict__ cst) {
    __shared__ float gsm[16 * 64];
    const int tid = threadIdx.x;
    const int lane = tid & 63;
    const int w = tid >> 6;
    const int quad = lane >> 4;
    const int l15 = lane & 15;
    const int j0 = blockIdx.x * 4;

    const short* arow = whh + ((l15 >> 2) * 1024 + j0 + (l15 & 3)) * 1024;
    const short* brow = hprev + (w * 16 + l15) * 1024;
    f32x4 acc = {0.f, 0.f, 0.f, 0.f};
#pragma unroll
    for (int k0 = 0; k0 < 1024; k0 += 32) {
        bf16x8 a = *(const bf16x8*)(arow + k0 + quad * 8);
        bf16x8 bb = *(const bf16x8*)(brow + k0 + quad * 8);
        acc = __builtin_amdgcn_mfma_f32_16x16x32_bf16(a, bb, acc, 0, 0, 0);
    }
#pragma unroll
    for (int r = 0; r < 4; r++) gsm[(quad * 4 + r) * 64 + w * 16 + l15] = acc[r];
    __syncthreads();

    const int b = tid & 63;
    const int jl = tid >> 6;
    const int j = j0 + jl;
    float gi = gsm[(0 + jl) * 64 + b] + pre_t[b * 4096 + j];
    float gf = gsm[(4 + jl) * 64 + b] + pre_t[b * 4096 + 1024 + j];
    float gg = gsm[(8 + jl) * 64 + b] + pre_t[b * 4096 + 2048 + j];
    float go = gsm[(12 + jl) * 64 + b] + pre_t[b * 4096 + 3072 + j];
    float iv = 1.f / (1.f + expf(-gi));
    float fv = 1.f / (1.f + expf(-gf));
    float gv = tanhf(gg);
    float ov = 1.f / (1.f + expf(-go));
    const int ci = b * 1024 + j;
    float cn = fv * cst[ci] + iv * gv;
    cst[ci] = cn;
    hnext[ci] = f2b(ov * tanhf(cn));
}

// ---------------------------------------------------------------------------
extern "C" void kernel_launch(void* const* d_in, const int* in_sizes, int n_in,
                              void* d_out, int out_size, void* d_ws, size_t ws_size,
                              hipStream_t stream) {
    (void)in_sizes; (void)n_in; (void)out_size; (void)ws_size;

    const int* src = (const int*)d_in[0];
    // d_in[1] source_lengths: unused by the reference
    const int* pos = (const int*)d_in[2];
    const int* tgt = (const int*)d_in[3];
    const float* enc_emb = (const float*)d_in[4];
    const float* pos_emb = (const float*)d_in[5];
    const float* cat_W = (const float*)d_in[6];
    const float* cat_b = (const float*)d_in[7];
    const float* scale_W = (const float*)d_in[8];
    const float* scale_b = (const float*)d_in[9];
    const float* dec_emb = (const float*)d_in[10];
    const float* attn_W = (const float*)d_in[11];
    // d_in[12] attn_b: shift-invariant under softmax, unused
    const float* W_ih = (const float*)d_in[13];
    const float* W_hh = (const float*)d_in[14];
    const float* b_ih = (const float*)d_in[15];
    const float* b_hh = (const float*)d_in[16];
    const float* proj_W = (const float*)d_in[17];
    const float* proj_b = (const float*)d_in[18];
    float* out = (float*)d_out;

    // workspace layout (byte offsets, all 256-aligned)
    char* ws = (char*)d_ws;
    short* H_ALL = (short*)(ws + 0);              // 3264 x 1024 bf16 = 6,684,672
    float* ENCO  = (float*)(ws + 6684672);        // 3200 x 512  f32 = 6,553,600
    float* CST   = (float*)(ws + 13238272);       // 64 x 1024   f32 =   262,144
    float* CTX   = (float*)(ws + 13500416);       // 64 x 512    f32 =   131,072
    float* PRE   = (float*)(ws + 13631488);       // 3136 x 4096 f32 = 51,380,224
    short* CATW  = (short*)(ws + 65011712);       // 512 x 1024  bf16 = 1,048,576
    short* WIH   = (short*)(ws + 66060288);       // 4096 x 1024 bf16 = 8,388,608
    short* WHH   = (short*)(ws + 74448896);       // 4096 x 1024 bf16 = 8,388,608
    short* PROJ  = (short*)(ws + 82837504);       // 32000 x 1024 bf16 = 65,536,000
    // total: 148,373,504 bytes

    // 0. weights f32 -> bf16
    cvt_kernel<<<512, 256, 0, stream>>>(cat_W, CATW, 131072);
    cvt_kernel<<<4096, 256, 0, stream>>>(W_ih, WIH, 1048576);
    cvt_kernel<<<4096, 256, 0, stream>>>(W_hh, WHH, 1048576);
    cvt_kernel<<<32000, 256, 0, stream>>>(proj_W, PROJ, 8192000);

    // 1. encoder: enc_out = [emb|pos] @ cat_W.T + cat_b   (f32 out)
    gemm_bt<0><<<dim3(4, 25), 256, 0, stream>>>(enc_emb, pos_emb, nullptr, src, pos,
                                                CATW, cat_b, nullptr, ENCO);
    // 2. h0 (= c0)
    h0_kernel<<<64, 256, 0, stream>>>(ENCO, scale_W, scale_b, H_ALL, CST);
    // 3. time-invariant attention context
    attn_kernel<<<64, 256, 0, stream>>>(ENCO, attn_W, src, CTX);
    // 4. pre[t*64+b] = [dec_emb[tok] | ctx] @ W_ih.T + b_ih + b_hh
    gemm_bt<1><<<dim3(32, 25), 256, 0, stream>>>(dec_emb, CTX, nullptr, tgt, nullptr,
                                                 WIH, b_ih, b_hh, PRE);
    // 5. 49 sequential LSTM steps (h_t appended into H_ALL)
    for (int t = 0; t < 49; t++)
        lstm_step<<<256, 256, 0, stream>>>(H_ALL + t * 65536, H_ALL + (t + 1) * 65536,
                                           PRE + t * 64 * 4096, WHH, CST);
    // 6. logits = h_all @ proj_W.T + proj_b   (f32 out)
    gemm_bt<2><<<dim3(250, 25), 256, 0, stream>>>(nullptr, nullptr, H_ALL + 65536,
                                                  nullptr, nullptr, PROJ, proj_b, nullptr, out);
}